// Round 2
// baseline (779.011 us; speedup 1.0000x reference)
//
#include <hip/hip_runtime.h>
#include <math.h>

namespace {
constexpr int B_ = 256, T_ = 256, LOD = 64, LSD = 128, ACTD = 32, K_ = 15, H_ = 60;
constexpr int NB = 7;     // band width (|i-j| <= 3)
constexpr int BROW = 9;   // LDS band row stride (coprime with 32 banks)

// LDS layout (float offsets)
constexpr int O_W1 = 0;                     // 32*60
constexpr int O_W2 = O_W1 + ACTD*H_;        // 60*128
constexpr int O_CW = O_W2 + H_*LSD;         // 128*15
constexpr int O_B1 = O_CW + LSD*K_;         // 60
constexpr int O_B2 = O_B1 + H_;             // 128
constexpr int O_CB = O_B2 + LSD;            // 16
constexpr int O_TCU = O_CB + 16;            // 64
constexpr int O_TCL = O_TCU + LOD;          // 64
constexpr int O_PM  = O_TCL + LOD;          // 128 prior mean (state)
constexpr int O_CU  = O_PM + LSD;           // 64  state covs
constexpr int O_CL  = O_CU + LOD;
constexpr int O_CS  = O_CL + LOD;
constexpr int O_MU  = O_CS + LOD;           // 72 padded post-mean upper
constexpr int O_ML  = O_MU + 72;            // 72 padded post-mean lower
constexpr int O_PCU = O_ML + 72;            // 72 padded post covs
constexpr int O_PCL = O_PCU + 72;
constexpr int O_PCS = O_PCL + 72;
constexpr int O_ACT = O_PCS + 72;           // 32
constexpr int O_H   = O_ACT + ACTD;         // 60
constexpr int O_CTRL= O_H + H_;             // 128
constexpr int O_PART= O_CTRL + LSD;         // 120 logit partials
constexpr int O_BANDS = O_PART + K_*8;      // 4*64*9
constexpr int O_END = O_BANDS + 4*64*BROW;  // total ~15176 floats < 64KB

constexpr long long NBT = (long long)B_*T_;
constexpr long long OO1 = NBT*LSD;          // pcu
constexpr long long OO2 = OO1 + NBT*LOD;    // pcl
constexpr long long OO3 = OO2 + NBT*LOD;    // pcs
constexpr long long OO4 = OO3 + NBT*LOD;    // npm
constexpr long long OO5 = OO4 + NBT*LSD;    // ncu
constexpr long long OO6 = OO5 + NBT*LOD;    // ncl
constexpr long long OO7 = OO6 + NBT*LOD;    // ncs
}

__global__ __launch_bounds__(256, 1)
void rkn_scan_kernel(const float* __restrict__ g_obs, const float* __restrict__ g_ovar,
                     const float* __restrict__ g_act, const float* __restrict__ g_im,
                     const float* __restrict__ g_icov, const float* __restrict__ g_cw,
                     const float* __restrict__ g_cb, const float* __restrict__ g_w1,
                     const float* __restrict__ g_b1, const float* __restrict__ g_w2,
                     const float* __restrict__ g_b2, const float* __restrict__ g_tmb,
                     const float* __restrict__ g_tcu, const float* __restrict__ g_tcl,
                     const int* __restrict__ g_valid, float* __restrict__ out)
{
    __shared__ float sm[O_END];
    __shared__ int svalid;

    const int t = threadIdx.x;
    const int b = blockIdx.x;
    const int lane = t & 63;
    const int f = t >> 6;      // wave id = which transition matrix this thread blends
    const int i = t & 63;      // row within the 64x64 matrix

    // ---- one-time block init: weights + state into LDS ----
    for (int idx = t; idx < ACTD*H_; idx += 256) sm[O_W1+idx] = g_w1[idx];
    for (int idx = t; idx < H_*LSD;  idx += 256) sm[O_W2+idx] = g_w2[idx];
    for (int idx = t; idx < LSD*K_;  idx += 256) sm[O_CW+idx] = g_cw[idx];
    if (t < H_)  sm[O_B1+t] = g_b1[t];
    if (t < LSD) sm[O_B2+t] = g_b2[t];
    if (t < K_)  sm[O_CB+t] = g_cb[t];
    if (t < LOD) {
        float x = g_tcu[t]; sm[O_TCU+t] = (x >= 0.f) ? x + 1.f : expf(x);
        float y = g_tcl[t]; sm[O_TCL+t] = (y >= 0.f) ? y + 1.f : expf(y);
        sm[O_CU+t] = g_icov[0*B_*LOD + b*LOD + t];
        sm[O_CL+t] = g_icov[1*B_*LOD + b*LOD + t];
        sm[O_CS+t] = g_icov[2*B_*LOD + b*LOD + t];
    }
    if (t < LSD) sm[O_PM+t] = g_im[b*LSD + t];
    for (int idx = t; idx < 5*72; idx += 256) sm[O_MU+idx] = 0.f; // zero all pads

    // ---- banded basis into registers: thread (f,i) holds basis[f][k][i][d] ----
    float bas[K_][NB];
    #pragma unroll
    for (int k = 0; k < K_; ++k) {
        #pragma unroll
        for (int d = 0; d < NB; ++d) {
            int j = i - 3 + d;
            bas[k][d] = (j >= 0 && j < LOD)
                ? g_tmb[(((long long)f*K_ + k)*LOD + i)*LOD + j] : 0.f;
        }
    }

    // ---- input prefetch registers (2 steps ahead) ----
    float obs0=0.f, ov0=0.f, obs1=0.f, ov1=0.f, a0=0.f, a1=0.f;
    int v0=0, v1=0;
    if (t < LOD) {
        obs0 = g_obs [((long long)b*T_+0)*LOD + t];
        ov0  = g_ovar[((long long)b*T_+0)*LOD + t];
        obs1 = g_obs [((long long)b*T_+1)*LOD + t];
        ov1  = g_ovar[((long long)b*T_+1)*LOD + t];
    }
    if (t < ACTD) {
        a0 = g_act[((long long)b*T_+0)*ACTD + t];
        a1 = g_act[((long long)b*T_+1)*ACTD + t];
        sm[O_ACT+t] = a0;
    }
    if (t == 0) {
        v0 = g_valid[b*T_ + 0];
        v1 = g_valid[b*T_ + 1];
        svalid = v0;
    }
    __syncthreads();

    #pragma unroll 1
    for (int tt = 0; tt < T_; ++tt) {
        const long long bt = (long long)b*T_ + tt;

        // ---- PA: Kalman update (wave0) | ctrl-MLP layer1 (threads 64..123) ----
        if (t < LOD) {
            float cuv = sm[O_CU+i], clv = sm[O_CL+i], csv = sm[O_CS+i];
            float pmu = sm[O_PM+i], pml = sm[O_PM+64+i];
            float denom = cuv + ov0;
            float qu = cuv / denom;
            float ql = csv / denom;
            float res = obs0 - pmu;
            float pu, pl, pcu, pcl, pcs;
            if (svalid) {
                pu = pmu + qu*res;  pl = pml + ql*res;
                float covf = 1.f - qu;
                pcu = covf*cuv;  pcl = clv - ql*csv;  pcs = covf*csv;
            } else {
                pu = pmu; pl = pml; pcu = cuv; pcl = clv; pcs = csv;
            }
            sm[O_MU+3+i] = pu;   sm[O_ML+3+i] = pl;
            sm[O_PCU+3+i] = pcu; sm[O_PCL+3+i] = pcl; sm[O_PCS+3+i] = pcs;
            out[bt*LSD + i]       = pu;
            out[bt*LSD + 64 + i]  = pl;
            out[OO1 + bt*LOD + i] = pcu;
            out[OO2 + bt*LOD + i] = pcl;
            out[OO3 + bt*LOD + i] = pcs;
        } else if (t < 64 + H_) {
            int j = t - 64;
            float acc = sm[O_B1+j];
            #pragma unroll
            for (int a = 0; a < ACTD; ++a) acc += sm[O_ACT+a] * sm[O_W1 + a*H_ + j];
            sm[O_H+j] = fmaxf(acc, 0.f);
        }
        __syncthreads();

        // ---- PB: shift+issue prefetch (t+2) | logit partials (t<120) | MLP layer2 ----
        obs0 = obs1; ov0 = ov1; a0 = a1; v0 = v1;
        {
            int tn = (tt + 2 < T_) ? tt + 2 : T_ - 1;
            if (t < LOD) {
                obs1 = g_obs [((long long)b*T_+tn)*LOD + t];
                ov1  = g_ovar[((long long)b*T_+tn)*LOD + t];
            }
            if (t < ACTD) a1 = g_act[((long long)b*T_+tn)*ACTD + t];
            if (t == 0)   v1 = g_valid[b*T_ + tn];
        }
        if (t < 120) {
            int k = t >> 3, p = t & 7, j0 = p*16;
            const float* src = (p < 4) ? &sm[O_MU+3+j0] : &sm[O_ML+3+j0-64];
            float acc = 0.f;
            #pragma unroll
            for (int jj = 0; jj < 16; ++jj) acc += src[jj] * sm[O_CW + (j0+jj)*K_ + k];
            sm[O_PART + t] = acc;   // part[k*8+p] == part[t]
        } else if (t >= 128) {
            int ii = t - 128;
            float acc = sm[O_B2+ii];
            #pragma unroll
            for (int j = 0; j < H_; ++j) acc += sm[O_H+j] * sm[O_W2 + j*LSD + ii];
            sm[O_CTRL+ii] = acc;
        }
        __syncthreads();

        // ---- PD: per-wave softmax (redundant, saves a barrier) + blend + band write ----
        float coef;
        {
            int g = lane & 15;
            float s = -3.0e38f;
            if (g < K_) {
                s = sm[O_CB+g];
                #pragma unroll
                for (int p = 0; p < 8; ++p) s += sm[O_PART + g*8 + p];
            }
            float m = s;
            #pragma unroll
            for (int off = 1; off < 16; off <<= 1) m = fmaxf(m, __shfl_xor(m, off, 16));
            float e = (g < K_) ? expf(s - m) : 0.f;
            float ssum = e;
            #pragma unroll
            for (int off = 1; off < 16; off <<= 1) ssum += __shfl_xor(ssum, off, 16);
            coef = e / ssum;
        }
        float bnd[NB];
        #pragma unroll
        for (int d = 0; d < NB; ++d) bnd[d] = 0.f;
        #pragma unroll
        for (int k = 0; k < K_; ++k) {
            float ck = __shfl(coef, k, 16);
            #pragma unroll
            for (int d = 0; d < NB; ++d) bnd[d] += ck * bas[k][d];
        }
        if (f == 0 || f == 3) bnd[3] += 1.f;   // + identity on diagonal (d=3 -> j=i)
        {
            int base = O_BANDS + (f*64 + i)*BROW;
            #pragma unroll
            for (int d = 0; d < NB; ++d) sm[base + d] = bnd[d];
        }
        __syncthreads();

        // ---- PE: mean/cov propagation (4-way role split), state update, outputs ----
        {
            const float* bd = &sm[O_BANDS];
            if (f == 0) {                       // nmu -> npm upper
                float acc = sm[O_CTRL+i];
                #pragma unroll
                for (int d = 0; d < NB; ++d)
                    acc += bd[(0*64+i)*BROW+d]*sm[O_MU+i+d]
                         + bd[(1*64+i)*BROW+d]*sm[O_ML+i+d];
                sm[O_PM+i] = acc;
                out[OO4 + bt*LSD + i] = acc;
                if (t < ACTD) sm[O_ACT+t] = a0;   // stage next step's action
                if (t == 0) svalid = v0;
            } else if (f == 1) {                // nml -> npm lower, plus ncs
                float acc = sm[O_CTRL+64+i];
                float ncs = 0.f;
                #pragma unroll
                for (int d = 0; d < NB; ++d) {
                    float Ad = bd[(0*64+i)*BROW+d], Bd = bd[(1*64+i)*BROW+d];
                    float Cd = bd[(2*64+i)*BROW+d], Dd = bd[(3*64+i)*BROW+d];
                    acc += Cd*sm[O_MU+i+d] + Dd*sm[O_ML+i+d];
                    float pu = sm[O_PCU+i+d], ps = sm[O_PCS+i+d], pl = sm[O_PCL+i+d];
                    ncs += Ad*(Cd*pu + Dd*ps) + Bd*(Cd*ps + Dd*pl);
                }
                sm[O_PM+64+i] = acc;
                out[OO4 + bt*LSD + 64 + i] = acc;
                sm[O_CS+i] = ncs;
                out[OO7 + bt*LOD + i] = ncs;
            } else if (f == 2) {                // ncu
                float acc = sm[O_TCU+i];
                #pragma unroll
                for (int d = 0; d < NB; ++d) {
                    float Ad = bd[(0*64+i)*BROW+d], Bd = bd[(1*64+i)*BROW+d];
                    float pu = sm[O_PCU+i+d], ps = sm[O_PCS+i+d], pl = sm[O_PCL+i+d];
                    acc += Ad*Ad*pu + 2.f*Ad*Bd*ps + Bd*Bd*pl;
                }
                sm[O_CU+i] = acc;
                out[OO5 + bt*LOD + i] = acc;
            } else {                            // ncl
                float acc = sm[O_TCL+i];
                #pragma unroll
                for (int d = 0; d < NB; ++d) {
                    float Cd = bd[(2*64+i)*BROW+d], Dd = bd[(3*64+i)*BROW+d];
                    float pu = sm[O_PCU+i+d], ps = sm[O_PCS+i+d], pl = sm[O_PCL+i+d];
                    acc += Cd*Cd*pu + 2.f*Cd*Dd*ps + Dd*Dd*pl;
                }
                sm[O_CL+i] = acc;
                out[OO6 + bt*LOD + i] = acc;
            }
        }
        __syncthreads();
    }
}

extern "C" void kernel_launch(void* const* d_in, const int* in_sizes, int n_in,
                              void* d_out, int out_size, void* d_ws, size_t ws_size,
                              hipStream_t stream) {
    (void)in_sizes; (void)n_in; (void)d_ws; (void)ws_size; (void)out_size;
    rkn_scan_kernel<<<B_, 256, 0, stream>>>(
        (const float*)d_in[0],  (const float*)d_in[1],  (const float*)d_in[2],
        (const float*)d_in[3],  (const float*)d_in[4],  (const float*)d_in[5],
        (const float*)d_in[6],  (const float*)d_in[7],  (const float*)d_in[8],
        (const float*)d_in[9],  (const float*)d_in[10], (const float*)d_in[11],
        (const float*)d_in[12], (const float*)d_in[13], (const int*)d_in[14],
        (float*)d_out);
}

// Round 4
// 711.313 us; speedup vs baseline: 1.0952x; 1.0952x over previous
//
#include <hip/hip_runtime.h>
#include <math.h>

namespace {
constexpr int B_=256, T_=256;
constexpr int NB=7;
constexpr int CH=8;            // steps per staged chunk
constexpr int NCH=T_/CH;       // 32 chunks

// LDS float offsets
constexpr int O_W1 = 0;                 // [32][60]
constexpr int O_W2 = O_W1+32*60;        // [60][128]
constexpr int O_B1 = O_W2+60*128;       // 60 (pad 64)
constexpr int O_B2 = O_B1+64;           // 128
constexpr int O_TCU= O_B2+128;          // 64
constexpr int O_TCL= O_TCU+64;          // 64
constexpr int O_PM = O_TCL+64;          // 128 state mean
constexpr int O_CU = O_PM+128;          // 64  state covs
constexpr int O_CL = O_CU+64;
constexpr int O_CS = O_CL+64;
constexpr int O_MU = O_CS+64;           // 72 padded update arrays
constexpr int O_ML = O_MU+72;
constexpr int O_PCU= O_ML+72;
constexpr int O_PCL= O_PCU+72;
constexpr int O_PCS= O_PCL+72;
constexpr int O_BND= O_PCS+72;          // bands [g][d][64] = 1792
constexpr int O_LG = O_BND+4*7*64;      // 16 logits
constexpr int O_OBS= O_LG+16;           // [CH][64]
constexpr int O_OV = O_OBS+CH*64;       // [CH][64]
constexpr int O_ACT= O_OV+CH*64;        // [CH][32]
constexpr int O_CT = O_ACT+CH*32;       // [CH][128] ctrl
constexpr int O_H  = O_CT+CH*128;       // [CH][60]  hidden
constexpr int O_END= O_H+CH*60;         // 15192 floats = 60768 B

constexpr long long NBT = (long long)B_*T_;
constexpr long long OO1 = NBT*128;          // pcu
constexpr long long OO2 = OO1 + NBT*64;     // pcl
constexpr long long OO3 = OO2 + NBT*64;     // pcs
constexpr long long OO4 = OO3 + NBT*64;     // npm
constexpr long long OO5 = OO4 + NBT*128;    // ncu
constexpr long long OO6 = OO5 + NBT*64;     // ncl
constexpr long long OO7 = OO6 + NBT*64;     // ncs
}

template <int CTRL>
__device__ __forceinline__ float dpp_add(float x) {
    int v = __builtin_amdgcn_update_dpp(0, __float_as_int(x), CTRL, 0xf, 0xf, false);
    return x + __int_as_float(v);
}
// full-wave (64-lane) sum, same value in all lanes' row-16 partials + readlane combine
__device__ __forceinline__ float wave_red64(float x) {
    x = dpp_add<0xB1>(x);    // quad_perm [1,0,3,2]  (xor 1)
    x = dpp_add<0x4E>(x);    // quad_perm [2,3,0,1]  (xor 2)
    x = dpp_add<0x124>(x);   // row_ror:4
    x = dpp_add<0x128>(x);   // row_ror:8 -> each lane has its row16 sum
    float a = __int_as_float(__builtin_amdgcn_readlane(__float_as_int(x), 16));
    float b = __int_as_float(__builtin_amdgcn_readlane(__float_as_int(x), 32));
    float c = __int_as_float(__builtin_amdgcn_readlane(__float_as_int(x), 48));
    return x + a + b + c;
}

__global__ __launch_bounds__(256, 1)
void rkn_scan_kernel(const float* __restrict__ g_obs, const float* __restrict__ g_ovar,
                     const float* __restrict__ g_act, const float* __restrict__ g_im,
                     const float* __restrict__ g_icov, const float* __restrict__ g_cw,
                     const float* __restrict__ g_cb, const float* __restrict__ g_w1,
                     const float* __restrict__ g_b1, const float* __restrict__ g_w2,
                     const float* __restrict__ g_b2, const float* __restrict__ g_tmb,
                     const float* __restrict__ g_tcu, const float* __restrict__ g_tcl,
                     const int* __restrict__ g_valid, float* __restrict__ out)
{
    __shared__ __align__(16) float sm[O_END];
    __shared__ int s_val[CH];

    const int t = threadIdx.x;
    const int b = blockIdx.x;
    const int f = t >> 6;       // wave id = matrix owned (0:A 1:B 2:C 3:D)
    const int i = t & 63;       // row / state index

    // ---------------- prologue: weights + state into LDS ----------------
    for (int idx = t; idx < 32*60;  idx += 256) sm[O_W1+idx] = g_w1[idx];
    for (int idx = t; idx < 60*128; idx += 256) sm[O_W2+idx] = g_w2[idx];
    if (t < 60)  sm[O_B1+t] = g_b1[t];
    if (t < 128) sm[O_B2+t] = g_b2[t];
    if (t < 64) {
        float x = g_tcu[t]; sm[O_TCU+t] = (x >= 0.f) ? x + 1.f : __expf(x);
        float y = g_tcl[t]; sm[O_TCL+t] = (y >= 0.f) ? y + 1.f : __expf(y);
        sm[O_CU+t] = g_icov[0*B_*64 + b*64 + t];
        sm[O_CL+t] = g_icov[1*B_*64 + b*64 + t];
        sm[O_CS+t] = g_icov[2*B_*64 + b*64 + t];
    }
    if (t < 128) sm[O_PM+t] = g_im[b*128 + t];
    for (int idx = t; idx < 5*72; idx += 256) sm[O_MU+idx] = 0.f;  // zero pads once

    // coeff_w columns for this wave's 4 logits, in registers
    float cwa[4], cwb[4], cbq[4];
    #pragma unroll
    for (int q = 0; q < 4; ++q) {
        int k = 4*f + q;
        bool ok = (k < 15);
        cwa[q] = ok ? g_cw[i*15 + k]      : 0.f;
        cwb[q] = ok ? g_cw[(64+i)*15 + k] : 0.f;
        cbq[q] = ok ? g_cb[k] * (1.f/64.f) : 0.f;
    }

    // banded basis in registers: lane (f,i) holds basis[f][k][i][d]
    float bas[15][NB];
    #pragma unroll
    for (int k = 0; k < 15; ++k) {
        #pragma unroll
        for (int d = 0; d < NB; ++d) {
            int j = i - 3 + d;
            bas[k][d] = (j >= 0 && j < 64)
                ? g_tmb[(((long long)f*15 + k)*64 + i)*64 + j] : 0.f;
        }
    }

    // per-batch input base pointers
    const float* pobs = g_obs  + (size_t)b*T_*64;
    const float* pov  = g_ovar + (size_t)b*T_*64;
    const float* pact = g_act  + (size_t)b*T_*32;
    const int*   pval = g_valid + (size_t)b*T_;
    const size_t bt0  = (size_t)b*T_;

    // prefetch regs: chunk 0
    float4 pfA = {0,0,0,0}, pfB = {0,0,0,0};
    int vpf = 0;
    {
        if (t < 128)  pfA = *(const float4*)(pobs + t*4);
        else          pfA = *(const float4*)(pov + (t-128)*4);
        if (t < 64)   pfB = *(const float4*)(pact + t*4);
        if (t >= 64 && t < 64+CH) vpf = pval[t-64];
    }

    float h0 = 0.f, h1 = 0.f;   // deferred P3 stores

    #pragma unroll 1
    for (int c = 0; c < NCH; ++c) {
        // ---- stage chunk c from prefetch regs ----
        if (t < 128)  *(float4*)&sm[O_OBS + t*4] = pfA;
        else          *(float4*)&sm[O_OV + (t-128)*4] = pfA;
        if (t < 64)   *(float4*)&sm[O_ACT + t*4] = pfB;
        if (t >= 64 && t < 64+CH) s_val[t-64] = vpf;
        __syncthreads();

        // ---- issue loads for chunk c+1 (drain covered by MLP bursts) ----
        if (c + 1 < NCH) {
            const int co = (c+1)*CH;
            if (t < 128)  pfA = *(const float4*)(pobs + co*64 + t*4);
            else          pfA = *(const float4*)(pov  + co*64 + (t-128)*4);
            if (t < 64)   pfB = *(const float4*)(pact + co*32 + t*4);
            if (t >= 64 && t < 64+CH) vpf = pval[co + t-64];
        }

        // ---- MLP burst 1: h[s][j] = relu(act@W1+b1), CH*64 slots ----
        #pragma unroll 1
        for (int r = 0; r < 2; ++r) {
            int slot = t + r*256;
            int s = slot >> 6, j = slot & 63;
            if (j < 60) {
                float acc = sm[O_B1+j];
                #pragma unroll
                for (int a = 0; a < 32; ++a)
                    acc += sm[O_ACT + s*32 + a] * sm[O_W1 + a*60 + j];
                sm[O_H + s*60 + j] = fmaxf(acc, 0.f);
            }
        }
        __syncthreads();

        // ---- MLP burst 2: ctrl[s][ii] = h@W2+b2, CH*128 slots ----
        #pragma unroll 1
        for (int r = 0; r < 4; ++r) {
            int slot = t + r*256;
            int s = slot >> 7, ii = slot & 127;
            float acc = sm[O_B2+ii];
            #pragma unroll
            for (int j = 0; j < 60; ++j)
                acc += sm[O_H + s*60 + j] * sm[O_W2 + j*128 + ii];
            sm[O_CT + s*128 + ii] = acc;
        }
        __syncthreads();

        // ================= 8 scan steps =================
        #pragma unroll 1
        for (int s = 0; s < CH; ++s) {
            const int tt = c*CH + s;
            const size_t bt = bt0 + tt;

            // --- P1: deferred P3 stores of step tt-1 ---
            if (tt > 0) {
                const size_t bp = bt - 1;
                if (f == 0)      { out[OO4 + bp*128 + i] = h0; out[OO4 + bp*128 + 64 + i] = h1; }
                else if (f == 1)   out[OO5 + bp*64 + i] = h0;
                else if (f == 2)   out[OO7 + bp*64 + i] = h0;
                else               out[OO6 + bp*64 + i] = h0;
            }

            // redundant Kalman update (all 4 waves)
            float cuv = sm[O_CU+i], clv = sm[O_CL+i], csv = sm[O_CS+i];
            float pmu = sm[O_PM+i], pml = sm[O_PM+64+i];
            float ob  = sm[O_OBS + s*64 + i], ovv = sm[O_OV + s*64 + i];
            const int vld = s_val[s];
            float inv = 1.f/(cuv + ovv);
            float qu = cuv*inv, ql = csv*inv;
            float res = ob - pmu;
            float covf = 1.f - qu;
            float pu  = vld ? pmu + qu*res : pmu;
            float pl  = vld ? pml + ql*res : pml;
            float pcu = vld ? covf*cuv     : cuv;
            float pcl = vld ? clv - ql*csv : clv;
            float pcs = vld ? covf*csv     : csv;

            // split writes of update arrays (padded +3)
            if (f == 0)      { sm[O_MU+3+i] = pu; sm[O_ML+3+i] = pl; }
            else if (f == 1)   sm[O_PCU+3+i] = pcu;
            else if (f == 2)   sm[O_PCL+3+i] = pcl;
            else               sm[O_PCS+3+i] = pcs;

            // logit partials for this wave's 4 k's + DPP wave reduce
            float p0 = cbq[0] + pu*cwa[0] + pl*cwb[0];
            float p1 = cbq[1] + pu*cwa[1] + pl*cwb[1];
            float p2 = cbq[2] + pu*cwa[2] + pl*cwb[2];
            float p3 = cbq[3] + pu*cwa[3] + pl*cwb[3];
            p0 = wave_red64(p0); p1 = wave_red64(p1);
            p2 = wave_red64(p2); p3 = wave_red64(p3);
            if (i == 0) {
                sm[O_LG + 4*f + 0] = p0; sm[O_LG + 4*f + 1] = p1;
                sm[O_LG + 4*f + 2] = p2; sm[O_LG + 4*f + 3] = p3;
            }
            __syncthreads();   // b1: logits + update arrays visible

            // --- P2: deferred stores of P1 outputs ---
            if (f == 0)      { out[bt*128 + i] = pu; out[bt*128 + 64 + i] = pl; }
            else if (f == 1)   out[OO1 + bt*64 + i] = pcu;
            else if (f == 2)   out[OO2 + bt*64 + i] = pcl;
            else               out[OO3 + bt*64 + i] = pcs;

            // redundant per-lane softmax over 15 logits
            float lgv[15];
            #pragma unroll
            for (int k = 0; k < 15; ++k) lgv[k] = sm[O_LG+k];
            float mx = lgv[0];
            #pragma unroll
            for (int k = 1; k < 15; ++k) mx = fmaxf(mx, lgv[k]);
            float ssum = 0.f;
            #pragma unroll
            for (int k = 0; k < 15; ++k) { lgv[k] = __expf(lgv[k]-mx); ssum += lgv[k]; }
            float isv = 1.f/ssum;

            // blend this wave's matrix band (reg-resident basis)
            float bnd[NB] = {0,0,0,0,0,0,0};
            #pragma unroll
            for (int k = 0; k < 15; ++k) {
                #pragma unroll
                for (int d = 0; d < NB; ++d) bnd[d] += lgv[k]*bas[k][d];
            }
            #pragma unroll
            for (int d = 0; d < NB; ++d) bnd[d] *= isv;
            if (f == 0 || f == 3) bnd[3] += 1.f;   // + eye on diagonal
            #pragma unroll
            for (int d = 0; d < NB; ++d) sm[O_BND + (f*7+d)*64 + i] = bnd[d];
            __syncthreads();   // b2: bands visible

            // --- P3: role-split propagation ---
            if (f == 0) {            // nmu, nml (owns A in bnd regs)
                float nmu = sm[O_CT + s*128 + i];
                float nml = sm[O_CT + s*128 + 64 + i];
                #pragma unroll
                for (int d = 0; d < NB; ++d) {
                    float mu_ = sm[O_MU+i+d], ml_ = sm[O_ML+i+d];
                    float Bv = sm[O_BND + (1*7+d)*64 + i];
                    float Cv = sm[O_BND + (2*7+d)*64 + i];
                    float Dv = sm[O_BND + (3*7+d)*64 + i];
                    nmu += bnd[d]*mu_ + Bv*ml_;
                    nml += Cv*mu_ + Dv*ml_;
                }
                sm[O_PM+i] = nmu; sm[O_PM+64+i] = nml;
                h0 = nmu; h1 = nml;
            } else if (f == 1) {     // ncu (owns B)
                float acc = sm[O_TCU+i];
                #pragma unroll
                for (int d = 0; d < NB; ++d) {
                    float Av = sm[O_BND + (0*7+d)*64 + i];
                    float Bv = bnd[d];
                    float puv = sm[O_PCU+i+d], psv = sm[O_PCS+i+d], plv = sm[O_PCL+i+d];
                    acc += Av*Av*puv + 2.f*Av*Bv*psv + Bv*Bv*plv;
                }
                sm[O_CU+i] = acc; h0 = acc;
            } else if (f == 2) {     // ncs (owns C)
                float acc = 0.f;
                #pragma unroll
                for (int d = 0; d < NB; ++d) {
                    float Av = sm[O_BND + (0*7+d)*64 + i];
                    float Bv = sm[O_BND + (1*7+d)*64 + i];
                    float Dv = sm[O_BND + (3*7+d)*64 + i];
                    float Cv = bnd[d];
                    float puv = sm[O_PCU+i+d], psv = sm[O_PCS+i+d], plv = sm[O_PCL+i+d];
                    acc += Av*(Cv*puv + Dv*psv) + Bv*(Cv*psv + Dv*plv);
                }
                sm[O_CS+i] = acc; h0 = acc;
            } else {                 // ncl (owns D)
                float acc = sm[O_TCL+i];
                #pragma unroll
                for (int d = 0; d < NB; ++d) {
                    float Cv = sm[O_BND + (2*7+d)*64 + i];
                    float Dv = bnd[d];
                    float puv = sm[O_PCU+i+d], psv = sm[O_PCS+i+d], plv = sm[O_PCL+i+d];
                    acc += Cv*Cv*puv + 2.f*Cv*Dv*psv + Dv*Dv*plv;
                }
                sm[O_CL+i] = acc; h0 = acc;
            }
            __syncthreads();   // b3: state visible
        }
    }

    // epilogue: deferred stores of step T-1
    {
        const size_t bp = bt0 + (T_-1);
        if (f == 0)      { out[OO4 + bp*128 + i] = h0; out[OO4 + bp*128 + 64 + i] = h1; }
        else if (f == 1)   out[OO5 + bp*64 + i] = h0;
        else if (f == 2)   out[OO7 + bp*64 + i] = h0;
        else               out[OO6 + bp*64 + i] = h0;
    }
}

extern "C" void kernel_launch(void* const* d_in, const int* in_sizes, int n_in,
                              void* d_out, int out_size, void* d_ws, size_t ws_size,
                              hipStream_t stream) {
    (void)in_sizes; (void)n_in; (void)d_ws; (void)ws_size; (void)out_size;
    rkn_scan_kernel<<<B_, 256, 0, stream>>>(
        (const float*)d_in[0],  (const float*)d_in[1],  (const float*)d_in[2],
        (const float*)d_in[3],  (const float*)d_in[4],  (const float*)d_in[5],
        (const float*)d_in[6],  (const float*)d_in[7],  (const float*)d_in[8],
        (const float*)d_in[9],  (const float*)d_in[10], (const float*)d_in[11],
        (const float*)d_in[12], (const float*)d_in[13], (const int*)d_in[14],
        (float*)d_out);
}